// Round 16
// baseline (206.793 us; speedup 1.0000x reference)
//
#include <hip/hip_runtime.h>
#include <hip/hip_bf16.h>
#include <cstdint>
#include <cstddef>

// RWKV6 TimeMix forward, MI355X. B=2 T=2048 C=1024 H=16 N=64.
#define B_ 2
#define T_ 2048
#define C_ 1024
#define H_ 16
#define NCH 32   // chunks per sequence
#define CHL 64   // chunk length

typedef unsigned short ushort_t;
typedef __bf16 bf16x8 __attribute__((ext_vector_type(8)));
typedef float f32x4 __attribute__((ext_vector_type(4)));

__device__ __forceinline__ ushort_t f2bf(float f) {
  union { float f; uint32_t u; } x; x.f = f;
  uint32_t r = x.u + 0x7fffu + ((x.u >> 16) & 1u);
  return (ushort_t)(r >> 16);
}
__device__ __forceinline__ float bf2f(ushort_t h) {
  union { uint32_t u; float f; } x; x.u = (uint32_t)h << 16; return x.f;
}

__device__ __forceinline__ void gload16(const void* g, void* l) {
  __builtin_amdgcn_global_load_lds(
      (const __attribute__((address_space(1))) void*)g,
      (__attribute__((address_space(3))) void*)l, 16, 0, 0);
}

#define FENCE() asm volatile("" ::: "memory")
#define BAR() do { FENCE(); __builtin_amdgcn_s_barrier(); FENCE(); } while (0)

// XOR-swizzled 64x64 bf16 tile helpers (row stride 128B, T2-style swizzle)
__device__ __forceinline__ void stb(ushort_t* tile, int row, int col, ushort_t v) {
  *(ushort_t*)((char*)tile + row * 128 + ((col * 2) ^ ((row & 7) << 4))) = v;
}
__device__ __forceinline__ bf16x8 ldb(const ushort_t* tile, int row, int kbyte) {
  return *(const bf16x8*)((const char*)tile + row * 128 + (kbyte ^ ((row & 7) << 4)));
}

// ---- init: z<9 weight transpose+cvt; z=9 prep (xh,xxh,xxx bf16) ----------
struct TDesc { const float* src; ushort_t* dst; int R, Cc, Cpad; };
struct TArgs { TDesc d[9]; };

__global__ __launch_bounds__(256) void init_kernel(
    TArgs args, const float* __restrict__ x, const float* __restrict__ tmx,
    ushort_t* __restrict__ xh, ushort_t* __restrict__ xxh,
    ushort_t* __restrict__ xxx) {
  if (blockIdx.z < 9) {
    TDesc D = args.d[blockIdx.z];
    int c0 = blockIdx.x * 32, r0 = blockIdx.y * 32;
    if (c0 >= D.Cpad || r0 >= D.R) return;
    __shared__ float tile[32][33];
    int tx = threadIdx.x & 31, ty = threadIdx.x >> 5;
#pragma unroll
    for (int i = 0; i < 32; i += 8) {
      int r = r0 + ty + i, c = c0 + tx;
      tile[ty + i][tx] = (r < D.R && c < D.Cc) ? D.src[(size_t)r * D.Cc + c] : 0.f;
    }
    __syncthreads();
#pragma unroll
    for (int i = 0; i < 32; i += 8) {
      int c = c0 + ty + i, r = r0 + tx;
      if (c < D.Cpad && r < D.R) D.dst[(size_t)c * D.R + r] = f2bf(tile[tx][ty + i]);
    }
    return;
  }
  // prep: 1024 blocks x 256 thr x 4 reps x 4 elems = B*T*C
  int lin = (blockIdx.y * 32 + blockIdx.x) * 256 + threadIdx.x;
#pragma unroll
  for (int rep = 0; rep < 4; ++rep) {
    size_t idx = ((size_t)(rep * 262144 + lin)) * 4;
    int tt = (int)((idx >> 10) & (T_ - 1));
    int c = (int)(idx & (C_ - 1));
    float4 xv = *(const float4*)&x[idx];
    float4 xp;
    if (tt == 0) { xp.x = xp.y = xp.z = xp.w = 0.f; }
    else xp = *(const float4*)&x[idx - C_];
    float4 tm = *(const float4*)&tmx[c];
    float4 d;
    d.x = xp.x - xv.x; d.y = xp.y - xv.y; d.z = xp.z - xv.z; d.w = xp.w - xv.w;
    ushort4 a, b, cc;
    a.x = f2bf(xv.x); a.y = f2bf(xv.y); a.z = f2bf(xv.z); a.w = f2bf(xv.w);
    b.x = f2bf(d.x);  b.y = f2bf(d.y);  b.z = f2bf(d.z);  b.w = f2bf(d.w);
    cc.x = f2bf(xv.x + d.x * tm.x); cc.y = f2bf(xv.y + d.y * tm.y);
    cc.z = f2bf(xv.z + d.z * tm.z); cc.w = f2bf(xv.w + d.w * tm.w);
    *(ushort4*)&xh[idx] = a;
    *(ushort4*)&xxh[idx] = b;
    *(ushort4*)&xxx[idx] = cc;
  }
}

// ---------------- bf16 MFMA GEMM 128x128, C = A * Bt^T (f32 out) -----------
__global__ __launch_bounds__(256) void gemm_bt(
    const ushort_t* __restrict__ A, int lda,
    const ushort_t* __restrict__ Bt, int ldb,
    float* __restrict__ Cp, int ldc, int K) {
  __shared__ ushort_t sA[128 * 32];
  __shared__ ushort_t sB[128 * 32];
  const int t = threadIdx.x;
  const int l = t & 63;
  const int w = t >> 6;
  const int wm = w >> 1, wn = w & 1;
  const int m0 = blockIdx.x * 128, n0 = blockIdx.y * 128;
  const int lr = l & 15;
  const int lk = (l >> 4) * 8;

  f32x4 acc[4][4] = {};

  for (int kt = 0; kt < K; kt += 32) {
    __syncthreads();
#pragma unroll
    for (int it = 0; it < 2; ++it) {
      int cbase = it * 256 + w * 64;
      int ca = cbase + l;
      int row = ca >> 2, kc = ca & 3;
      gload16(A + (size_t)(m0 + row) * lda + kt + kc * 8, (char*)sA + (size_t)cbase * 16);
      gload16(Bt + (size_t)(n0 + row) * ldb + kt + kc * 8, (char*)sB + (size_t)cbase * 16);
    }
    __syncthreads();
    bf16x8 af[4], bfr[4];
#pragma unroll
    for (int mi = 0; mi < 4; ++mi)
      af[mi] = *(const bf16x8*)&sA[(wm * 64 + mi * 16 + lr) * 32 + lk];
#pragma unroll
    for (int ni = 0; ni < 4; ++ni)
      bfr[ni] = *(const bf16x8*)&sB[(wn * 64 + ni * 16 + lr) * 32 + lk];
#pragma unroll
    for (int mi = 0; mi < 4; ++mi)
#pragma unroll
      for (int ni = 0; ni < 4; ++ni)
        acc[mi][ni] = __builtin_amdgcn_mfma_f32_16x16x32_bf16(af[mi], bfr[ni], acc[mi][ni], 0, 0, 0);
  }
#pragma unroll
  for (int mi = 0; mi < 4; ++mi) {
#pragma unroll
    for (int ni = 0; ni < 4; ++ni) {
      int col = n0 + wn * 64 + ni * 16 + lr;
#pragma unroll
      for (int r = 0; r < 4; ++r) {
        int row = m0 + wm * 64 + mi * 16 + (l >> 4) * 4 + r;
        Cp[(size_t)row * ldc + col] = acc[mi][ni][r];
      }
    }
  }
}

// ---------------- narrow GEMM 32x128 tile, tanh->bf16 ----------------------
__global__ __launch_bounds__(256) void gemm_bt32(
    const ushort_t* __restrict__ A, int lda,
    const ushort_t* __restrict__ Bt, int ldb,
    ushort_t* __restrict__ Cp, int ldc, int K) {
  __shared__ ushort_t sA[32 * 32];
  __shared__ ushort_t sB[128 * 32];
  const int t = threadIdx.x;
  const int l = t & 63;
  const int w = t >> 6;          // wave -> 32-col quarter of N
  const int m0 = blockIdx.x * 32, n0 = blockIdx.y * 128;
  const int lr = l & 15, lk = (l >> 4) * 8;

  f32x4 acc[2][2] = {};
  for (int kt = 0; kt < K; kt += 32) {
    __syncthreads();
    if (t < 128) {
      int row = t >> 2, kc = t & 3;
      gload16(A + (size_t)(m0 + row) * lda + kt + kc * 8, (char*)sA + t * 16);
    }
#pragma unroll
    for (int it = 0; it < 2; ++it) {
      int ca = it * 256 + t;
      int row = ca >> 2, kc = ca & 3;
      gload16(Bt + (size_t)(n0 + row) * ldb + kt + kc * 8,
              (char*)sB + it * 4096 + w * 1024);
    }
    __syncthreads();
    bf16x8 af[2], bfr[2];
#pragma unroll
    for (int mi = 0; mi < 2; ++mi)
      af[mi] = *(const bf16x8*)&sA[(mi * 16 + lr) * 32 + lk];
#pragma unroll
    for (int ni = 0; ni < 2; ++ni)
      bfr[ni] = *(const bf16x8*)&sB[(w * 32 + ni * 16 + lr) * 32 + lk];
#pragma unroll
    for (int mi = 0; mi < 2; ++mi)
#pragma unroll
      for (int ni = 0; ni < 2; ++ni)
        acc[mi][ni] = __builtin_amdgcn_mfma_f32_16x16x32_bf16(af[mi], bfr[ni], acc[mi][ni], 0, 0, 0);
  }
#pragma unroll
  for (int mi = 0; mi < 2; ++mi)
#pragma unroll
    for (int ni = 0; ni < 2; ++ni) {
      int col = n0 + w * 32 + ni * 16 + lr;
#pragma unroll
      for (int r = 0; r < 4; ++r) {
        int row = m0 + mi * 16 + (l >> 4) * 4 + r;
        Cp[(size_t)row * ldc + col] = f2bf(tanhf(acc[mi][ni][r]));
      }
    }
}

// ------- 256x128 BK=32 2-blocks/CU pipelined GEMM (proj r,k,v,g + t5d) -----
// 512 thr, 8 waves (2M x 4N), tile 256x128, BK=32. LDS 48KB -> 2 blocks/CU.
// Per K-tile: one compiler-scheduled compute region (10 ds_read + 16 MFMA),
// BAR, stage tile j+2 (3 gloads), counted vmcnt(3) (tail: vmcnt(0) at j=30).
// Zero-conflict 64B-row layout: slot = (hi4 ^ ((lr>>1)&3)); source carries
// the same involution. EPI: 0 = f32, 2 = silu->bf16, 3 = bf16, 4 = tanh->bf16.
struct PDesc { const ushort_t* A; const ushort_t* Bt; void* C; int epi; int ldc; };
struct PArgs { PDesc d[5]; };

__global__ __launch_bounds__(512, 2) void gemm_proj256(PArgs args) {
  if (blockIdx.z == 4 && blockIdx.y > 0) return;   // t5d slice: N=128 only
  PDesc D = args.d[blockIdx.z];
  __shared__ ushort_t sMem[2][3][4096];   // [buf][unit: A0,A1,B][8KB]
  const int tid = threadIdx.x;
  const int w = tid >> 6, l = tid & 63;
  const int wm = w >> 2, wn = w & 3;
  const int lr = l & 15, hi4 = l >> 4;
  const int m0 = blockIdx.x * 256, n0 = blockIdx.y * 128;

  const int srow = tid >> 2;                           // 0..127
  const int schunk = (((tid & 3) ^ ((tid >> 3) & 3))) * 8;  // inverse-swizzled k
  const ushort_t* Ab0 = D.A + (size_t)(m0 + srow) * C_ + schunk;
  const ushort_t* Ab1 = Ab0 + (size_t)128 * C_;
  const ushort_t* Bb  = D.Bt + (size_t)(n0 + srow) * C_ + schunk;
  const int dst16 = tid * 16;
  const int slotA = (hi4 ^ ((lr >> 1) & 3)) << 4;

  f32x4 acc[8][2] = {};

#define STG(b, kt)                                              \
  do {                                                          \
    gload16(Ab0 + (kt), (char*)&sMem[b][0][0] + dst16);         \
    gload16(Ab1 + (kt), (char*)&sMem[b][1][0] + dst16);         \
    gload16(Bb  + (kt), (char*)&sMem[b][2][0] + dst16);         \
  } while (0)

#define LDA(b, mi) \
  (*(const bf16x8*)((const char*)&sMem[b][wm][0] + ((mi)*16 + lr) * 64 + slotA))
#define LDB(b, ni) \
  (*(const bf16x8*)((const char*)&sMem[b][2][0] + (wn * 32 + (ni)*16 + lr) * 64 + slotA))

#define COMP(b)                                                               \
  do {                                                                        \
    bf16x8 b0 = LDB(b, 0), b1 = LDB(b, 1);                                    \
    __builtin_amdgcn_s_setprio(1);                                            \
    _Pragma("unroll") for (int mi = 0; mi < 8; ++mi) {                        \
      bf16x8 af = LDA(b, mi);                                                 \
      acc[mi][0] = __builtin_amdgcn_mfma_f32_16x16x32_bf16(af, b0, acc[mi][0], 0, 0, 0); \
      acc[mi][1] = __builtin_amdgcn_mfma_f32_16x16x32_bf16(af, b1, acc[mi][1], 0, 0, 0); \
    }                                                                         \
    __builtin_amdgcn_s_setprio(0);                                            \
  } while (0)

#define BODY(b, jj)                                                           \
  do {                                                                        \
    COMP(b);                                                                  \
    BAR();                                                                    \
    if ((jj) < 30) {                                                          \
      STG(b, ((jj) + 2) * 32);                                                \
      asm volatile("s_waitcnt vmcnt(3)" ::: "memory");                        \
    } else if ((jj) == 30) {                                                  \
      asm volatile("s_waitcnt vmcnt(0)" ::: "memory");                        \
    }                                                                         \
    BAR();                                                                    \
  } while (0)

  // prologue: stage tiles 0 (buf0) and 1 (buf1); wait tile 0 landed
  STG(0, 0);
  STG(1, 32);
  asm volatile("s_waitcnt vmcnt(3)" ::: "memory");
  BAR();

#pragma unroll 1
  for (int j = 0; j < 32; j += 2) {
    BODY(0, j);
    BODY(1, j + 1);
  }
  asm volatile("s_waitcnt vmcnt(0)" ::: "memory");

  const int epi = D.epi;
  const int ldc = D.ldc;
#pragma unroll
  for (int mi = 0; mi < 8; ++mi)
#pragma unroll
    for (int ni = 0; ni < 2; ++ni) {
      int col = n0 + wn * 32 + ni * 16 + lr;
#pragma unroll
      for (int r = 0; r < 4; ++r) {
        int row = m0 + wm * 128 + mi * 16 + hi4 * 4 + r;
        float v = acc[mi][ni][r];
        size_t idx = (size_t)row * ldc + col;
        if (epi == 2) {
          v = v / (1.f + __expf(-v));
          ((ushort_t*)D.C)[idx] = f2bf(v);
        } else if (epi == 3) {
          ((ushort_t*)D.C)[idx] = f2bf(v);
        } else if (epi == 4) {
          ((ushort_t*)D.C)[idx] = f2bf(tanhf(v));
        } else {
          ((float*)D.C)[idx] = v;
        }
      }
    }
#undef BODY
#undef COMP
#undef LDB
#undef LDA
#undef STG
}

// ------- fused data-dependent mix (5 outputs, bf16 x/xx staged once) -------
struct MixArgs { const float* tm[5]; ushort_t* dst[5]; };

__global__ __launch_bounds__(256) void fused_mix(
    const ushort_t* __restrict__ xh, const ushort_t* __restrict__ xxh,
    const ushort_t* __restrict__ t5, const ushort_t* __restrict__ w2t,
    MixArgs margs) {
  __shared__ ushort_t xs[64 * 128];    // 16KB bf16
  __shared__ ushort_t xxs[64 * 128];   // 16KB bf16
  __shared__ ushort_t sA[64 * 32];
  __shared__ ushort_t sB[128 * 32];
  const int t = threadIdx.x;
  const int l = t & 63;
  const int w = t >> 6;
  const int wm = w >> 1, wn = w & 1;
  const int m0 = blockIdx.x * 64, n0 = blockIdx.y * 128;
  const int lr = l & 15;
  const int lk = (l >> 4) * 8;

#pragma unroll
  for (int it = 0; it < 4; ++it) {
    int row = it * 16 + (t >> 4);
    int c8 = t & 15;
    gload16(xh + (size_t)(m0 + row) * C_ + n0 + c8 * 8, (char*)xs + row * 256 + c8 * 16);
    gload16(xxh + (size_t)(m0 + row) * C_ + n0 + c8 * 8, (char*)xxs + row * 256 + c8 * 16);
  }

  for (int f = 0; f < 5; ++f) {
    __syncthreads();
    {
      int row = t >> 2, c8 = t & 3;
      gload16(t5 + (size_t)(m0 + row) * 256 + f * 32 + c8 * 8, (char*)sA + t * 16);
    }
#pragma unroll
    for (int it = 0; it < 2; ++it) {
      int row = it * 64 + (t >> 2), c8 = t & 3;
      gload16(w2t + (size_t)(n0 + row) * 160 + f * 32 + c8 * 8,
              (char*)sB + it * 4096 + t * 16);
    }
    __syncthreads();
    bf16x8 af[2], bfr[4];
#pragma unroll
    for (int mi = 0; mi < 2; ++mi)
      af[mi] = *(const bf16x8*)&sA[(wm * 32 + mi * 16 + lr) * 32 + lk];
#pragma unroll
    for (int ni = 0; ni < 4; ++ni)
      bfr[ni] = *(const bf16x8*)&sB[(wn * 64 + ni * 16 + lr) * 32 + lk];
    f32x4 acc[2][4] = {};
#pragma unroll
    for (int mi = 0; mi < 2; ++mi)
#pragma unroll
      for (int ni = 0; ni < 4; ++ni)
        acc[mi][ni] = __builtin_amdgcn_mfma_f32_16x16x32_bf16(af[mi], bfr[ni], acc[mi][ni], 0, 0, 0);
    const float* tmf = margs.tm[f];
    ushort_t* dst = margs.dst[f];
#pragma unroll
    for (int mi = 0; mi < 2; ++mi) {
#pragma unroll
      for (int ni = 0; ni < 4; ++ni) {
        int cl = wn * 64 + ni * 16 + lr;
        int col = n0 + cl;
        float tmv = tmf[col];
#pragma unroll
        for (int r = 0; r < 4; ++r) {
          int rl = wm * 32 + mi * 16 + (l >> 4) * 4 + r;
          int row = m0 + rl;
          float xv = bf2f(xs[rl * 128 + cl]);
          float xxv = bf2f(xxs[rl * 128 + cl]);
          dst[(size_t)row * C_ + col] = f2bf(xv + xxv * (tmv + acc[mi][ni][r]));
        }
      }
    }
  }
}

// ---------------- K1: chunk-local MFMA scan (+ fused lambda GEMM) ----------
__global__ __launch_bounds__(256) void chunk_local(
    const ushort_t* __restrict__ rxh, const ushort_t* __restrict__ kxh,
    const float* __restrict__ vx, const ushort_t* __restrict__ t5d,
    const ushort_t* __restrict__ w2t, const float* __restrict__ tdec,
    const float* __restrict__ u, float* __restrict__ Mt,
    float* __restrict__ aLg, ushort_t* __restrict__ rAg,
    ushort_t* __restrict__ yo) {
  int c = blockIdx.x, bh = blockIdx.y;
  int b = bh >> 4, h = bh & 15;
  __shared__ ushort_t sRA[64 * 64], sKA[64 * 64], sKh[64 * 64], sKl[64 * 64],
                      sVh[64 * 64], sVl[64 * 64], sP[64 * 64];
  __shared__ float sLam[64 * 64];   // 16KB: lambda tile [t][i]
  __shared__ float qsum[4][64];
  __shared__ float ruk[64];
  const int tid = threadIdx.x;
  const int i = tid & 63;       // channel lane
  const int q = tid >> 6;       // t-quarter / wave
  size_t base = ((size_t)b * T_ + (size_t)c * CHL) * C_ + h * 64;
  size_t cb = ((size_t)c * 32 + bh);
  const int trow0 = b * T_ + c * CHL;

  const int lr0 = tid & 15, hi0 = (tid & 63) >> 4;

  // ---- phase 0: fused lambda GEMM: sLam[t][i] = exp(tdec + t5d@w2) --------
#pragma unroll
  for (int p = 0; p < 2; ++p) {
    int L = p * 256 + tid;
    int r = L >> 3, u8 = L & 7;
    int sc = (u8 ^ (r & 7)) * 8;
    gload16(t5d + (size_t)(trow0 + r) * 128 + sc, (char*)sRA + L * 16);
    gload16(w2t + (size_t)(h * 64 + r) * 64 + sc, (char*)sKA + L * 16);
  }
  asm volatile("s_waitcnt vmcnt(0)" ::: "memory");
  __syncthreads();
  {
    f32x4 accL[4] = {};
#pragma unroll
    for (int kk = 0; kk < 2; ++kk) {
      bf16x8 bw = ldb(sKA, q * 16 + lr0, kk * 64 + hi0 * 16);
#pragma unroll
      for (int mi = 0; mi < 4; ++mi) {
        bf16x8 at = ldb(sRA, mi * 16 + lr0, kk * 64 + hi0 * 16);
        accL[mi] = __builtin_amdgcn_mfma_f32_16x16x32_bf16(at, bw, accL[mi], 0, 0, 0);
      }
    }
    float tdv = tdec[h * 64 + q * 16 + lr0];
#pragma unroll
    for (int mi = 0; mi < 4; ++mi)
#pragma unroll
      for (int rr = 0; rr < 4; ++rr)
        sLam[(mi * 16 + hi0 * 4 + rr) * 64 + q * 16 + lr0] = __expf(tdv + accL[mi][rr]);
  }
  __syncthreads();

  // ---- phase A: lambda cumsum + tile builds ----
  float lam[16];
  float run = 0.f;
#pragma unroll
  for (int s = 0; s < 16; ++s) {
    lam[s] = sLam[(q * 16 + s) * 64 + i];
    run += lam[s];
  }
  qsum[q][i] = run;
  __syncthreads();
  float pre = 0.f, ct = 0.f;
#pragma unroll
  for (int qq = 0; qq < 4; ++qq) {
    float vq = qsum[qq][i];
    ct += vq;
    if (qq < q) pre += vq;
  }
  float uu = u[h * 64 + i];
  float ci = pre;
#pragma unroll
  for (int s = 0; s < 16; ++s) {
    int t = q * 16 + s;
    ci += lam[s];
    float cl = ci - lam[s];
    size_t o = base + (size_t)t * C_ + i;
    float rv = bf2f(rxh[o]), kv = bf2f(kxh[o]), vv = vx[o];
    ushort_t ra = f2bf(rv * __expf(-cl));
    stb(sRA, t, i, ra);
    rAg[cb * 4096 + t * 64 + i] = ra;
    stb(sKA, t, i, f2bf(kv * __expf(ci)));
    float kal = kv * __expf(ci - ct);
    ushort_t khv = f2bf(kal);
    stb(sKh, i, t, khv);
    stb(sKl, i, t, f2bf(kal - bf2f(khv)));
    ushort_t vhv = f2bf(vv);
    stb(sVh, i, t, vhv);
    stb(sVl, i, t, f2bf(vv - bf2f(vhv)));
    float rr = rv * uu * kv;
#pragma unroll
    for (int m = 32; m; m >>= 1) rr += __shfl_xor(rr, m);
    if (i == 0) ruk[t] = rr;
  }
  if (q == 0) aLg[cb * 64 + i] = __expf(-ct);
  __syncthreads();

  const int l = tid & 63, w = tid >> 6;
  const int wm = w >> 1, wn = w & 1;
  const int lr = l & 15, hi4 = l >> 4;

  // ---- phase B: P = rA @ kA^T, mask, store bf16 ----
  {
    f32x4 accP[2][2] = {};
#pragma unroll
    for (int kk = 0; kk < 2; ++kk) {
      bf16x8 af[2], bf_[2];
#pragma unroll
      for (int mi = 0; mi < 2; ++mi) af[mi] = ldb(sRA, wm * 32 + mi * 16 + lr, kk * 64 + hi4 * 16);
#pragma unroll
      for (int ni = 0; ni < 2; ++ni) bf_[ni] = ldb(sKA, wn * 32 + ni * 16 + lr, kk * 64 + hi4 * 16);
#pragma unroll
      for (int mi = 0; mi < 2; ++mi)
#pragma unroll
        for (int ni = 0; ni < 2; ++ni)
          accP[mi][ni] = __builtin_amdgcn_mfma_f32_16x16x32_bf16(af[mi], bf_[ni], accP[mi][ni], 0, 0, 0);
    }
#pragma unroll
    for (int mi = 0; mi < 2; ++mi)
#pragma unroll
      for (int ni = 0; ni < 2; ++ni)
#pragma unroll
        for (int r = 0; r < 4; ++r) {
          int tl = wm * 32 + mi * 16 + hi4 * 4 + r, sl = wn * 32 + ni * 16 + lr;
          float v = accP[mi][ni][r];
          v = sl < tl ? v : (sl == tl ? ruk[tl] : 0.f);
          stb(sP, tl, sl, f2bf(v));
        }
  }
  __syncthreads();

  // ---- phase C: y_intra = P@(Vh+Vl);  Mt = (Vh+Vl)^T @ (kh+kl) ----
  f32x4 accY[2][2] = {}, accM[2][2] = {};
#pragma unroll
  for (int kk = 0; kk < 2; ++kk) {
    bf16x8 pa[2], vhA[2], vlA[2], vhB[2], vlB[2], khB[2], klB[2];
#pragma unroll
    for (int mi = 0; mi < 2; ++mi) {
      int rw = wm * 32 + mi * 16 + lr;
      pa[mi] = ldb(sP, rw, kk * 64 + hi4 * 16);
      vhA[mi] = ldb(sVh, rw, kk * 64 + hi4 * 16);
      vlA[mi] = ldb(sVl, rw, kk * 64 + hi4 * 16);
    }
#pragma unroll
    for (int ni = 0; ni < 2; ++ni) {
      int rw = wn * 32 + ni * 16 + lr;
      vhB[ni] = ldb(sVh, rw, kk * 64 + hi4 * 16);
      vlB[ni] = ldb(sVl, rw, kk * 64 + hi4 * 16);
      khB[ni] = ldb(sKh, rw, kk * 64 + hi4 * 16);
      klB[ni] = ldb(sKl, rw, kk * 64 + hi4 * 16);
    }
#pragma unroll
    for (int mi = 0; mi < 2; ++mi)
#pragma unroll
      for (int ni = 0; ni < 2; ++ni) {
        accY[mi][ni] = __builtin_amdgcn_mfma_f32_16x16x32_bf16(pa[mi], vhB[ni], accY[mi][ni], 0, 0, 0);
        accY[mi][ni] = __builtin_amdgcn_mfma_f32_16x16x32_bf16(pa[mi], vlB[ni], accY[mi][ni], 0, 0, 0);
        accM[mi][ni] = __builtin_amdgcn_mfma_f32_16x16x32_bf16(vhA[mi], khB[ni], accM[mi][ni], 0, 0, 0);
        accM[mi][ni] = __builtin_amdgcn_mfma_f32_16x16x32_bf16(vhA[mi], klB[ni], accM[mi][ni], 0, 0, 0);
        accM[mi][ni] = __builtin_amdgcn_mfma_f32_16x16x32_bf16(vlA[mi], khB[ni], accM[mi][ni], 0, 0, 0);
      }
  }
#pragma unroll
  for (int mi = 0; mi < 2; ++mi)
#pragma unroll
    for (int ni = 0; ni < 2; ++ni)
#pragma unroll
      for (int r = 0; r < 4; ++r) {
        int rw = wm * 32 + mi * 16 + hi4 * 4 + r;
        int cw = wn * 32 + ni * 16 + lr;
        yo[base + (size_t)rw * C_ + cw] = f2bf(accY[mi][ni][r]);  // y_intra bf16
        Mt[cb * 4096 + rw * 64 + cw] = accM[mi][ni][r];           // Mt[j][i]
      }
}

// ---------------- K2: sequential chunk combine (prefetched, vec4) ----------
__global__ __launch_bounds__(128) void combine2(
    const float* __restrict__ Mt, const float* __restrict__ aLg,
    ushort_t* __restrict__ S0h, ushort_t* __restrict__ S0l) {
  int bh = blockIdx.x >> 3;
  int ij = ((blockIdx.x & 7) * 128 + threadIdx.x) * 4;   // [j][i] linear, 4-wide
  int i = ij & 63;
  const float* Mp = Mt + (size_t)bh * 4096 + ij;
  const float* Pp = aLg + (size_t)bh * 64 + i;
  ushort_t* Hp = S0h + (size_t)bh * 4096 + ij;
  ushort_t* Lp = S0l + (size_t)bh * 4096 + ij;
  float4 s = {0.f, 0.f, 0.f, 0.f};
  float4 m = *(const float4*)Mp;
  float4 p = *(const float4*)Pp;
  for (int c = 0; c < NCH; ++c) {
    float4 mn, pn;
    if (c < NCH - 1) {
      mn = *(const float4*)(Mp + (size_t)(c + 1) * (32 * 4096));
      pn = *(const float4*)(Pp + (size_t)(c + 1) * (32 * 64));
    }
    size_t o = (size_t)c * (32 * 4096);
    ushort4 hi, lo;
    hi.x = f2bf(s.x); lo.x = f2bf(s.x - bf2f(hi.x));
    hi.y = f2bf(s.y); lo.y = f2bf(s.y - bf2f(hi.y));
    hi.z = f2bf(s.z); lo.z = f2bf(s.z - bf2f(hi.z));
    hi.w = f2bf(s.w); lo.w = f2bf(s.w - bf2f(hi.w));
    *(ushort4*)(Hp + o) = hi;
    *(ushort4*)(Lp + o) = lo;
    s.x = p.x * s.x + m.x; s.y = p.y * s.y + m.y;
    s.z = p.z * s.z + m.z; s.w = p.w * s.w + m.w;
    m = mn; p = pn;
  }
}

// ---------------- K3: y = y_intra + rA@S0, GroupNorm, *g -> bf16 Z ---------
__global__ __launch_bounds__(256) void inter_gn(
    const ushort_t* __restrict__ rAg, const ushort_t* __restrict__ S0h,
    const ushort_t* __restrict__ S0l, const ushort_t* __restrict__ yin,
    const ushort_t* __restrict__ gx, const float* __restrict__ lnw,
    const float* __restrict__ lnb, ushort_t* __restrict__ Z) {
  int c = blockIdx.x, bh = blockIdx.y;
  int b = bh >> 4, h = bh & 15;
  __shared__ ushort_t sRA[64 * 64], sSh[64 * 64], sSl[64 * 64];
  __shared__ float st[64][2][2];
  const int tid = threadIdx.x;
  size_t cb = ((size_t)c * 32 + bh) * 4096;
#pragma unroll
  for (int it = 0; it < 2; ++it) {
    int lb = tid * 32 + it * 16;
    int row = lb >> 7, wi = lb & 127;
    int so = row * 128 + (wi ^ ((row & 7) << 4));
    *(uint4*)((char*)sRA + so) = *(const uint4*)((const char*)(rAg + cb) + lb);
    *(uint4*)((char*)sSh + so) = *(const uint4*)((const char*)(S0h + cb) + lb);
    *(uint4*)((char*)sSl + so) = *(const uint4*)((const char*)(S0l + cb) + lb);
  }
  const int l = tid & 63, w = tid >> 6;
  const int wm = w >> 1, wn = w & 1;
  const int lr = l & 15, hi4 = l >> 4;
  size_t base = ((size_t)b * T_ + (size_t)c * CHL) * C_ + h * 64;

  f32x4 acc[2][2];
#pragma unroll
  for (int mi = 0; mi < 2; ++mi)
#pragma unroll
    for (int ni = 0; ni < 2; ++ni)
#pragma unroll
      for (int r = 0; r < 4; ++r)
        acc[mi][ni][r] = bf2f(yin[base + (size_t)(wm * 32 + mi * 16 + hi4 * 4 + r) * C_ +
                                  wn * 32 + ni * 16 + lr]);
  __syncthreads();
#pragma unroll
  for (int kk = 0; kk < 2; ++kk) {
    bf16x8 af[2], bh_[2], bl_[2];
#pragma unroll
    for (int mi = 0; mi < 2; ++mi) af[mi] = ldb(sRA, wm * 32 + mi * 16 + lr, kk * 64 + hi4 * 16);
#pragma unroll
    for (int ni = 0; ni < 2; ++ni) {
      bh_[ni] = ldb(sSh, wn * 32 + ni * 16 + lr, kk * 64 + hi4 * 16);
      bl_[ni] = ldb(sSl, wn * 32 + ni * 16 + lr, kk * 64 + hi4 * 16);
    }
#pragma unroll
    for (int mi = 0; mi < 2; ++mi)
#pragma unroll
      for (int ni = 0; ni < 2; ++ni) {
        acc[mi][ni] = __builtin_amdgcn_mfma_f32_16x16x32_bf16(af[mi], bh_[ni], acc[mi][ni], 0, 0, 0);
        acc[mi][ni] = __builtin_amdgcn_mfma_f32_16x16x32_bf16(af[mi], bl_[ni], acc[mi][ni], 0, 0, 0);
      }
  }
#pragma unroll
  for (int mi = 0; mi < 2; ++mi)
#pragma unroll
    for (int r = 0; r < 4; ++r) {
      int row = wm * 32 + mi * 16 + hi4 * 4 + r;
      float s1 = acc[mi][0][r] + acc[mi][1][r];
      float s2 = acc[mi][0][r] * acc[mi][0][r] + acc[mi][1][r] * acc[mi][1][r];
#pragma unroll
      for (int m = 1; m < 16; m <<= 1) { s1 += __shfl_xor(s1, m); s2 += __shfl_xor(s2, m); }
      if (lr == 0) { st[row][wn][0] = s1; st[row][wn][1] = s2; }
    }
  __syncthreads();
#pragma unroll
  for (int mi = 0; mi < 2; ++mi)
#pragma unroll
    for (int ni = 0; ni < 2; ++ni)
#pragma unroll
      for (int r = 0; r < 4; ++r) {
        int row = wm * 32 + mi * 16 + hi4 * 4 + r;
        int jl = wn * 32 + ni * 16 + lr;
        float S1 = st[row][0][0] + st[row][1][0];
        float S2 = st[row][0][1] + st[row][1][1];
        float mu = S1 * (1.f / 64.f);
        float var = S2 * (1.f / 64.f) - mu * mu;
        float rs = rsqrtf(var + 6.4e-4f);          // EPS = 1e-5 * 64
        int col = h * 64 + jl;
        size_t o = base + (size_t)row * C_ + jl;
        float yn = (acc[mi][ni][r] - mu) * rs * lnw[col] + lnb[col];
        Z[o] = f2bf(yn * bf2f(gx[o]));
      }
}

// ===========================================================================
extern "C" void kernel_launch(void* const* d_in, const int* in_sizes, int n_in,
                              void* d_out, int out_size, void* d_ws, size_t ws_size,
                              hipStream_t stream) {
  const float* x    = (const float*)d_in[0];
  const float* tmx  = (const float*)d_in[1];
  const float* tmw  = (const float*)d_in[2];
  const float* tmk  = (const float*)d_in[3];
  const float* tmv  = (const float*)d_in[4];
  const float* tmr  = (const float*)d_in[5];
  const float* tmg  = (const float*)d_in[6];
  const float* maaw1 = (const float*)d_in[7];
  const float* maaw2 = (const float*)d_in[8];
  const float* tdec = (const float*)d_in[9];
  const float* tdw1 = (const float*)d_in[10];
  const float* tdw2 = (const float*)d_in[11];
  const float* u    = (const float*)d_in[12];
  const float* Wr   = (const float*)d_in[13];
  const float* Wk   = (const float*)d_in[14];
  const float* Wv   = (const float*)d_in[15];
  const float* Wg   = (const float*)d_in[16];
  const float* Wo   = (const float*)d_in[17];
  const float* lnw  = (const float*)d_in[18];
  const float* lnb  = (const float*)d_in[19];

  char* ws = (char*)d_ws;
  const size_t MB = 1ull << 20;
  ushort_t* xh     = (ushort_t*)(ws + 0);         // 8MB  (later: yb)
  ushort_t* xxh    = (ushort_t*)(ws + 8 * MB);    // 8MB
  ushort_t* xxx    = (ushort_t*)(ws + 16 * MB);   // 8MB  (later: Zb)
  ushort_t* WrT    = (ushort_t*)(ws + 24 * MB);
  ushort_t* WkT    = (ushort_t*)(ws + 26 * MB);
  ushort_t* WvT    = (ushort_t*)(ws + 28 * MB);
  ushort_t* WgT    = (ushort_t*)(ws + 30 * MB);
  ushort_t* WoT    = (ushort_t*)(ws + 32 * MB);
  ushort_t* maaW1T = (ushort_t*)(ws + 34 * MB);              // 256x1024
  ushort_t* tdW1T  = (ushort_t*)(ws + 35 * MB);              // 128x1024
  ushort_t* tdW2T  = (ushort_t*)(ws + 35 * MB + 256 * 1024); // 1024x64
  ushort_t* maaW2T = (ushort_t*)(ws + 35 * MB + 512 * 1024); // 1024x160
  ushort_t* t5     = (ushort_t*)(ws + 36 * MB);   // 4096x256 bf16
  ushort_t* t5d    = (ushort_t*)(ws + 38 * MB);   // 4096x128 bf16
  ushort_t* Xm[5];
  for (int f = 0; f < 5; ++f) Xm[f] = (ushort_t*)(ws + 40 * MB + (size_t)f * 8 * MB);
  float*    Mtb = (float*)(ws + 40 * MB);          // 16MB  (over Xm[0..1], dead)
  ushort_t* S0h = (ushort_t*)(ws + 56 * MB);       // 8MB   (over Xm[2])
  ushort_t* S0l = (ushort_t*)(ws + 64 * MB);       // 8MB   (over Xm[3])
  ushort_t* rAg = (ushort_t*)(ws + 72 * MB);       // 8MB   (over Xm[4])
  ushort_t* rbh = (ushort_t*)(ws + 80 * MB);       // 8MB bf16 r
  ushort_t* kbh = (ushort_t*)(ws + 96 * MB);       // 8MB bf16 k
  float* vb   = (float*)(ws + 112 * MB);
  ushort_t* gbh = (ushort_t*)(ws + 128 * MB);      // 8MB bf16 gate
  float* aLg  = (float*)(ws + 144 * MB);           // 256KB
  ushort_t* yb = (ushort_t*)(ws + 0);              // bf16, alias xh (dead by then)
  ushort_t* Zb = (ushort_t*)(ws + 16 * MB);        // alias xxx (dead by then)

  // 1) weight transposes/converts + token-shift prep in ONE launch
  TArgs ta;
  ta.d[0] = TDesc{Wr,    WrT,    1024, 1024, 1024};
  ta.d[1] = TDesc{Wk,    WkT,    1024, 1024, 1024};
  ta.d[2] = TDesc{Wv,    WvT,    1024, 1024, 1024};
  ta.d[3] = TDesc{Wg,    WgT,    1024, 1024, 1024};
  ta.d[4] = TDesc{Wo,    WoT,    1024, 1024, 1024};
  ta.d[5] = TDesc{maaw1, maaW1T, 1024, 160,  256};
  ta.d[6] = TDesc{tdw1,  tdW1T,  1024, 64,   128};
  ta.d[7] = TDesc{tdw2,  tdW2T,  64,   1024, 1024};
  ta.d[8] = TDesc{maaw2, maaW2T, 160,  1024, 1024};
  init_kernel<<<dim3(32, 32, 10), 256, 0, stream>>>(ta, x, tmx, xh, xxh, xxx);

  // 2) t5 = tanh(xxx @ maa_w1)  (32-row tiles: 256 blocks, full CU coverage)
  gemm_bt32<<<dim3(128, 2), 256, 0, stream>>>(xxx, C_, maaW1T, C_, t5, 256, C_);

  // 3) fused per-f mix (bf16 staging)
  MixArgs ma;
  ma.tm[0] = tmw; ma.tm[1] = tmk; ma.tm[2] = tmv; ma.tm[3] = tmr; ma.tm[4] = tmg;
  for (int f = 0; f < 5; ++f) ma.dst[f] = Xm[f];
  fused_mix<<<dim3(64, 8), 256, 0, stream>>>(xh, xxh, t5, maaW2T, ma);

  // 4) projections r,k,v,g + t5d tanh-GEMM in ONE dispatch (z=5)
  PArgs pa;
  pa.d[0] = PDesc{Xm[3], WrT,   rbh, 3, C_};
  pa.d[1] = PDesc{Xm[1], WkT,   kbh, 3, C_};
  pa.d[2] = PDesc{Xm[2], WvT,   vb,  0, C_};
  pa.d[3] = PDesc{Xm[4], WgT,   gbh, 2, C_};
  pa.d[4] = PDesc{Xm[0], tdW1T, t5d, 4, 128};
  gemm_proj256<<<dim3(16, 8, 5), 512, 0, stream>>>(pa);

  // 5) MFMA chunked scan (fused lambda GEMM; y_intra in bf16)
  chunk_local<<<dim3(NCH, B_ * H_), 256, 0, stream>>>(rbh, kbh, vb, t5d, tdW2T, tdec,
                                                      u, Mtb, aLg, rAg, yb);
  combine2<<<256, 128, 0, stream>>>(Mtb, aLg, S0h, S0l);
  inter_gn<<<dim3(NCH, B_ * H_), 256, 0, stream>>>(rAg, S0h, S0l, yb, gbh, lnw, lnb, Zb);

  // 6) out = Z @ Wo — 128² tile, 256 blocks (full CU coverage)
  gemm_bt<<<dim3(32, 8), 256, 0, stream>>>(Zb, C_, WoT, C_, (float*)d_out, C_, C_);
}

// Round 17
// 198.959 us; speedup vs baseline: 1.0394x; 1.0394x over previous
//
#include <hip/hip_runtime.h>
#include <hip/hip_bf16.h>
#include <cstdint>
#include <cstddef>

// RWKV6 TimeMix forward, MI355X. B=2 T=2048 C=1024 H=16 N=64.
#define B_ 2
#define T_ 2048
#define C_ 1024
#define H_ 16
#define NCH 32   // chunks per sequence
#define CHL 64   // chunk length

typedef unsigned short ushort_t;
typedef __bf16 bf16x8 __attribute__((ext_vector_type(8)));
typedef float f32x4 __attribute__((ext_vector_type(4)));

__device__ __forceinline__ ushort_t f2bf(float f) {
  union { float f; uint32_t u; } x; x.f = f;
  uint32_t r = x.u + 0x7fffu + ((x.u >> 16) & 1u);
  return (ushort_t)(r >> 16);
}
__device__ __forceinline__ float bf2f(ushort_t h) {
  union { uint32_t u; float f; } x; x.u = (uint32_t)h << 16; return x.f;
}

__device__ __forceinline__ void gload16(const void* g, void* l) {
  __builtin_amdgcn_global_load_lds(
      (const __attribute__((address_space(1))) void*)g,
      (__attribute__((address_space(3))) void*)l, 16, 0, 0);
}

#define FENCE() asm volatile("" ::: "memory")
#define BAR() do { FENCE(); __builtin_amdgcn_s_barrier(); FENCE(); } while (0)

// XOR-swizzled 64x64 bf16 tile helpers (row stride 128B, T2-style swizzle)
__device__ __forceinline__ void stb(ushort_t* tile, int row, int col, ushort_t v) {
  *(ushort_t*)((char*)tile + row * 128 + ((col * 2) ^ ((row & 7) << 4))) = v;
}
__device__ __forceinline__ bf16x8 ldb(const ushort_t* tile, int row, int kbyte) {
  return *(const bf16x8*)((const char*)tile + row * 128 + (kbyte ^ ((row & 7) << 4)));
}

// ---- init: z<9 weight transpose+cvt; z=9 prep (xh,xxh,xxx bf16) ----------
struct TDesc { const float* src; ushort_t* dst; int R, Cc, Cpad; };
struct TArgs { TDesc d[9]; };

__global__ __launch_bounds__(256) void init_kernel(
    TArgs args, const float* __restrict__ x, const float* __restrict__ tmx,
    ushort_t* __restrict__ xh, ushort_t* __restrict__ xxh,
    ushort_t* __restrict__ xxx) {
  if (blockIdx.z < 9) {
    TDesc D = args.d[blockIdx.z];
    int c0 = blockIdx.x * 32, r0 = blockIdx.y * 32;
    if (c0 >= D.Cpad || r0 >= D.R) return;
    __shared__ float tile[32][33];
    int tx = threadIdx.x & 31, ty = threadIdx.x >> 5;
#pragma unroll
    for (int i = 0; i < 32; i += 8) {
      int r = r0 + ty + i, c = c0 + tx;
      tile[ty + i][tx] = (r < D.R && c < D.Cc) ? D.src[(size_t)r * D.Cc + c] : 0.f;
    }
    __syncthreads();
#pragma unroll
    for (int i = 0; i < 32; i += 8) {
      int c = c0 + ty + i, r = r0 + tx;
      if (c < D.Cpad && r < D.R) D.dst[(size_t)c * D.R + r] = f2bf(tile[tx][ty + i]);
    }
    return;
  }
  // prep: 1024 blocks x 256 thr x 4 reps x 4 elems = B*T*C
  int lin = (blockIdx.y * 32 + blockIdx.x) * 256 + threadIdx.x;
#pragma unroll
  for (int rep = 0; rep < 4; ++rep) {
    size_t idx = ((size_t)(rep * 262144 + lin)) * 4;
    int tt = (int)((idx >> 10) & (T_ - 1));
    int c = (int)(idx & (C_ - 1));
    float4 xv = *(const float4*)&x[idx];
    float4 xp;
    if (tt == 0) { xp.x = xp.y = xp.z = xp.w = 0.f; }
    else xp = *(const float4*)&x[idx - C_];
    float4 tm = *(const float4*)&tmx[c];
    float4 d;
    d.x = xp.x - xv.x; d.y = xp.y - xv.y; d.z = xp.z - xv.z; d.w = xp.w - xv.w;
    ushort4 a, b, cc;
    a.x = f2bf(xv.x); a.y = f2bf(xv.y); a.z = f2bf(xv.z); a.w = f2bf(xv.w);
    b.x = f2bf(d.x);  b.y = f2bf(d.y);  b.z = f2bf(d.z);  b.w = f2bf(d.w);
    cc.x = f2bf(xv.x + d.x * tm.x); cc.y = f2bf(xv.y + d.y * tm.y);
    cc.z = f2bf(xv.z + d.z * tm.z); cc.w = f2bf(xv.w + d.w * tm.w);
    *(ushort4*)&xh[idx] = a;
    *(ushort4*)&xxh[idx] = b;
    *(ushort4*)&xxx[idx] = cc;
  }
}

// ---------------- bf16 MFMA GEMM 128x128, C = A * Bt^T (f32 out) -----------
__global__ __launch_bounds__(256) void gemm_bt(
    const ushort_t* __restrict__ A, int lda,
    const ushort_t* __restrict__ Bt, int ldb,
    float* __restrict__ Cp, int ldc, int K) {
  __shared__ ushort_t sA[128 * 32];
  __shared__ ushort_t sB[128 * 32];
  const int t = threadIdx.x;
  const int l = t & 63;
  const int w = t >> 6;
  const int wm = w >> 1, wn = w & 1;
  const int m0 = blockIdx.x * 128, n0 = blockIdx.y * 128;
  const int lr = l & 15;
  const int lk = (l >> 4) * 8;

  f32x4 acc[4][4] = {};

  for (int kt = 0; kt < K; kt += 32) {
    __syncthreads();
#pragma unroll
    for (int it = 0; it < 2; ++it) {
      int cbase = it * 256 + w * 64;
      int ca = cbase + l;
      int row = ca >> 2, kc = ca & 3;
      gload16(A + (size_t)(m0 + row) * lda + kt + kc * 8, (char*)sA + (size_t)cbase * 16);
      gload16(Bt + (size_t)(n0 + row) * ldb + kt + kc * 8, (char*)sB + (size_t)cbase * 16);
    }
    __syncthreads();
    bf16x8 af[4], bfr[4];
#pragma unroll
    for (int mi = 0; mi < 4; ++mi)
      af[mi] = *(const bf16x8*)&sA[(wm * 64 + mi * 16 + lr) * 32 + lk];
#pragma unroll
    for (int ni = 0; ni < 4; ++ni)
      bfr[ni] = *(const bf16x8*)&sB[(wn * 64 + ni * 16 + lr) * 32 + lk];
#pragma unroll
    for (int mi = 0; mi < 4; ++mi)
#pragma unroll
      for (int ni = 0; ni < 4; ++ni)
        acc[mi][ni] = __builtin_amdgcn_mfma_f32_16x16x32_bf16(af[mi], bfr[ni], acc[mi][ni], 0, 0, 0);
  }
#pragma unroll
  for (int mi = 0; mi < 4; ++mi) {
#pragma unroll
    for (int ni = 0; ni < 4; ++ni) {
      int col = n0 + wn * 64 + ni * 16 + lr;
#pragma unroll
      for (int r = 0; r < 4; ++r) {
        int row = m0 + wm * 64 + mi * 16 + (l >> 4) * 4 + r;
        Cp[(size_t)row * ldc + col] = acc[mi][ni][r];
      }
    }
  }
}

// ---------------- narrow GEMM 32x128 tile, tanh->bf16 ----------------------
__global__ __launch_bounds__(256) void gemm_bt32(
    const ushort_t* __restrict__ A, int lda,
    const ushort_t* __restrict__ Bt, int ldb,
    ushort_t* __restrict__ Cp, int ldc, int K) {
  __shared__ ushort_t sA[32 * 32];
  __shared__ ushort_t sB[128 * 32];
  const int t = threadIdx.x;
  const int l = t & 63;
  const int w = t >> 6;          // wave -> 32-col quarter of N
  const int m0 = blockIdx.x * 32, n0 = blockIdx.y * 128;
  const int lr = l & 15, lk = (l >> 4) * 8;

  f32x4 acc[2][2] = {};
  for (int kt = 0; kt < K; kt += 32) {
    __syncthreads();
    if (t < 128) {
      int row = t >> 2, kc = t & 3;
      gload16(A + (size_t)(m0 + row) * lda + kt + kc * 8, (char*)sA + t * 16);
    }
#pragma unroll
    for (int it = 0; it < 2; ++it) {
      int ca = it * 256 + t;
      int row = ca >> 2, kc = ca & 3;
      gload16(Bt + (size_t)(n0 + row) * ldb + kt + kc * 8,
              (char*)sB + it * 4096 + w * 1024);
    }
    __syncthreads();
    bf16x8 af[2], bfr[2];
#pragma unroll
    for (int mi = 0; mi < 2; ++mi)
      af[mi] = *(const bf16x8*)&sA[(mi * 16 + lr) * 32 + lk];
#pragma unroll
    for (int ni = 0; ni < 2; ++ni)
      bfr[ni] = *(const bf16x8*)&sB[(w * 32 + ni * 16 + lr) * 32 + lk];
#pragma unroll
    for (int mi = 0; mi < 2; ++mi)
#pragma unroll
      for (int ni = 0; ni < 2; ++ni)
        acc[mi][ni] = __builtin_amdgcn_mfma_f32_16x16x32_bf16(af[mi], bfr[ni], acc[mi][ni], 0, 0, 0);
  }
#pragma unroll
  for (int mi = 0; mi < 2; ++mi)
#pragma unroll
    for (int ni = 0; ni < 2; ++ni) {
      int col = n0 + w * 32 + ni * 16 + lr;
#pragma unroll
      for (int r = 0; r < 4; ++r) {
        int row = m0 + mi * 16 + (l >> 4) * 4 + r;
        Cp[(size_t)row * ldc + col] = f2bf(tanhf(acc[mi][ni][r]));
      }
    }
}

// ---------------- 256x256 8-phase pipelined GEMM (proj r,k,v,g) ------------
// round-8 schedule (best measured). EPI: 0 = f32, 2 = silu->bf16, 3 = bf16.
struct PDesc { const ushort_t* A; const ushort_t* Bt; void* C; int epi; };
struct PArgs { PDesc d[4]; };

__global__ __launch_bounds__(512, 1) void gemm_proj256(PArgs args) {
  PDesc D = args.d[blockIdx.z];
  __shared__ ushort_t sMem[2][2][4][4096];   // [buf][A=0/B=1][unit][8KB]
  const int tid = threadIdx.x;
  const int w = tid >> 6, l = tid & 63;
  const int wm = w >> 2, wn = w & 3;
  const int lr = l & 15, hi4 = l >> 4;
  const int m0 = blockIdx.x * 256, n0 = blockIdx.y * 256;

  const int srow = tid >> 3;                          // row within 64-row unit
  const int scol = (((tid & 7) ^ (srow & 7)) << 3);   // inverse-swizzled k off
  const ushort_t* Abase = D.A + (size_t)(m0 + srow) * C_ + scol;
  const ushort_t* Bbase = D.Bt + (size_t)(n0 + srow) * C_ + scol;
  const int dst16 = tid * 16;

  f32x4 acc[8][4] = {};
  bf16x8 bfr[2][4];   // B frags for current tile, loaded at p0, live all 4 phases

#define STG_A(db, unit, kt) \
  gload16(Abase + (size_t)(unit) * 64 * C_ + (kt), (char*)&sMem[db][0][unit][0] + dst16)
#define STG_B(db, unit, kt) \
  gload16(Bbase + (size_t)(unit) * 64 * C_ + (kt), (char*)&sMem[db][1][unit][0] + dst16)

#define LDA_(b, p, i, kk)                                                      \
  (*(const bf16x8*)((const char*)&sMem[b][0][wm * 2 + ((p) >> 1)][0] +         \
                    (((2 * (p) + (i)) & 3) * 16 + lr) * 128 +                  \
                    ((((kk)*4 + hi4) ^ (lr & 7)) << 4)))
#define LDB_(b, ni, kk)                                                        \
  (*(const bf16x8*)((const char*)&sMem[b][1][wn][0] +                          \
                    ((ni)*16 + lr) * 128 + ((((kk)*4 + hi4) ^ (lr & 7)) << 4)))

#define PH(b, p, STAGES, VM)                                                   \
  do {                                                                         \
    bf16x8 a00, a10, a01, a11;                                                 \
    if ((p) == 0) {                                                            \
      _Pragma("unroll") for (int kk = 0; kk < 2; ++kk)                         \
      _Pragma("unroll") for (int ni = 0; ni < 4; ++ni)                         \
        bfr[kk][ni] = LDB_(b, ni, kk);                                         \
    }                                                                          \
    a00 = LDA_(b, p, 0, 0); a10 = LDA_(b, p, 1, 0);                            \
    a01 = LDA_(b, p, 0, 1); a11 = LDA_(b, p, 1, 1);                            \
    STAGES;                                                                    \
    VM;                                                                        \
    BAR();                                                                     \
    asm volatile("s_waitcnt lgkmcnt(0)" ::: "memory");                         \
    __builtin_amdgcn_sched_barrier(0);                                         \
    __builtin_amdgcn_s_setprio(1);                                             \
    _Pragma("unroll") for (int ni = 0; ni < 4; ++ni) {                         \
      acc[2 * (p)][ni] = __builtin_amdgcn_mfma_f32_16x16x32_bf16(              \
          a00, bfr[0][ni], acc[2 * (p)][ni], 0, 0, 0);                         \
      acc[2 * (p) + 1][ni] = __builtin_amdgcn_mfma_f32_16x16x32_bf16(          \
          a10, bfr[0][ni], acc[2 * (p) + 1][ni], 0, 0, 0);                     \
      acc[2 * (p)][ni] = __builtin_amdgcn_mfma_f32_16x16x32_bf16(              \
          a01, bfr[1][ni], acc[2 * (p)][ni], 0, 0, 0);                         \
      acc[2 * (p) + 1][ni] = __builtin_amdgcn_mfma_f32_16x16x32_bf16(          \
          a11, bfr[1][ni], acc[2 * (p) + 1][ni], 0, 0, 0);                     \
    }                                                                          \
    __builtin_amdgcn_s_setprio(0);                                             \
    BAR();                                                                     \
  } while (0)

#define TILE(b, kt1, kt2)                                                      \
  do {                                                                         \
    PH(b, 0, { STG_A((b) ^ 1, 1, kt1); STG_A((b) ^ 1, 3, kt1); }, );           \
    PH(b, 1, { STG_B(b, 0, kt2); STG_B(b, 1, kt2); },                          \
       asm volatile("s_waitcnt vmcnt(10)" ::: "memory"));                      \
    PH(b, 2, { STG_B(b, 2, kt2); STG_B(b, 3, kt2); }, );                       \
    PH(b, 3, { STG_A(b, 0, kt2); STG_A(b, 2, kt2); },                          \
       asm volatile("s_waitcnt vmcnt(8)" ::: "memory"));                       \
  } while (0)

  // prologue: 7 stage-pairs in steady-state FIFO order
  STG_B(0, 0, 0);  STG_B(0, 1, 0);     // pair 1: B01(0)
  STG_B(0, 2, 0);  STG_B(0, 3, 0);     // pair 2: B23(0)
  STG_A(0, 0, 0);  STG_A(0, 2, 0);     // pair 3: Au02(0)
  STG_A(0, 1, 0);  STG_A(0, 3, 0);     // pair 4: Au13(0)
  STG_B(1, 0, 64); STG_B(1, 1, 64);    // pair 5: B01(1)
  STG_B(1, 2, 64); STG_B(1, 3, 64);    // pair 6: B23(1)
  STG_A(1, 0, 64); STG_A(1, 2, 64);    // pair 7: Au02(1)
  asm volatile("s_waitcnt vmcnt(8)" ::: "memory");   // pairs 1-3 landed
  BAR();

#pragma unroll 1
  for (int j = 0; j < 16; j += 2) {
    int ka1 = ((j + 1) & 15) * 64, ka2 = ((j + 2) & 15) * 64;
    int kb1 = ((j + 2) & 15) * 64, kb2 = ((j + 3) & 15) * 64;
    TILE(0, ka1, ka2);
    TILE(1, kb1, kb2);
  }
  asm volatile("s_waitcnt vmcnt(0)" ::: "memory");

  const int epi = D.epi;
#pragma unroll
  for (int mi = 0; mi < 8; ++mi)
#pragma unroll
    for (int ni = 0; ni < 4; ++ni) {
      int col = n0 + wn * 64 + ni * 16 + lr;
#pragma unroll
      for (int r = 0; r < 4; ++r) {
        int row = m0 + wm * 128 + mi * 16 + hi4 * 4 + r;
        float v = acc[mi][ni][r];
        size_t idx = (size_t)row * C_ + col;
        if (epi == 2) {
          v = v / (1.f + __expf(-v));
          ((ushort_t*)D.C)[idx] = f2bf(v);
        } else if (epi == 3) {
          ((ushort_t*)D.C)[idx] = f2bf(v);
        } else {
          ((float*)D.C)[idx] = v;
        }
      }
    }
#undef TILE
#undef PH
#undef LDB_
#undef LDA_
#undef STG_B
#undef STG_A
}

// ------- fused data-dependent mix (5 outputs, bf16 x/xx staged once) -------
struct MixArgs { const float* tm[5]; ushort_t* dst[5]; };

__global__ __launch_bounds__(256) void fused_mix(
    const ushort_t* __restrict__ xh, const ushort_t* __restrict__ xxh,
    const ushort_t* __restrict__ t5, const ushort_t* __restrict__ w2t,
    MixArgs margs) {
  __shared__ ushort_t xs[64 * 128];    // 16KB bf16
  __shared__ ushort_t xxs[64 * 128];   // 16KB bf16
  __shared__ ushort_t sA[64 * 32];
  __shared__ ushort_t sB[128 * 32];
  const int t = threadIdx.x;
  const int l = t & 63;
  const int w = t >> 6;
  const int wm = w >> 1, wn = w & 1;
  const int m0 = blockIdx.x * 64, n0 = blockIdx.y * 128;
  const int lr = l & 15;
  const int lk = (l >> 4) * 8;

#pragma unroll
  for (int it = 0; it < 4; ++it) {
    int row = it * 16 + (t >> 4);
    int c8 = t & 15;
    gload16(xh + (size_t)(m0 + row) * C_ + n0 + c8 * 8, (char*)xs + row * 256 + c8 * 16);
    gload16(xxh + (size_t)(m0 + row) * C_ + n0 + c8 * 8, (char*)xxs + row * 256 + c8 * 16);
  }

  for (int f = 0; f < 5; ++f) {
    __syncthreads();
    {
      int row = t >> 2, c8 = t & 3;
      gload16(t5 + (size_t)(m0 + row) * 256 + f * 32 + c8 * 8, (char*)sA + t * 16);
    }
#pragma unroll
    for (int it = 0; it < 2; ++it) {
      int row = it * 64 + (t >> 2), c8 = t & 3;
      gload16(w2t + (size_t)(n0 + row) * 160 + f * 32 + c8 * 8,
              (char*)sB + it * 4096 + t * 16);
    }
    __syncthreads();
    bf16x8 af[2], bfr[4];
#pragma unroll
    for (int mi = 0; mi < 2; ++mi)
      af[mi] = *(const bf16x8*)&sA[(wm * 32 + mi * 16 + lr) * 32 + lk];
#pragma unroll
    for (int ni = 0; ni < 4; ++ni)
      bfr[ni] = *(const bf16x8*)&sB[(wn * 64 + ni * 16 + lr) * 32 + lk];
    f32x4 acc[2][4] = {};
#pragma unroll
    for (int mi = 0; mi < 2; ++mi)
#pragma unroll
      for (int ni = 0; ni < 4; ++ni)
        acc[mi][ni] = __builtin_amdgcn_mfma_f32_16x16x32_bf16(af[mi], bfr[ni], acc[mi][ni], 0, 0, 0);
    const float* tmf = margs.tm[f];
    ushort_t* dst = margs.dst[f];
#pragma unroll
    for (int mi = 0; mi < 2; ++mi) {
#pragma unroll
      for (int ni = 0; ni < 4; ++ni) {
        int cl = wn * 64 + ni * 16 + lr;
        int col = n0 + cl;
        float tmv = tmf[col];
#pragma unroll
        for (int r = 0; r < 4; ++r) {
          int rl = wm * 32 + mi * 16 + (l >> 4) * 4 + r;
          int row = m0 + rl;
          float xv = bf2f(xs[rl * 128 + cl]);
          float xxv = bf2f(xxs[rl * 128 + cl]);
          dst[(size_t)row * C_ + col] = f2bf(xv + xxv * (tmv + acc[mi][ni][r]));
        }
      }
    }
  }
}

// ---------------- K1: chunk-local MFMA scan (+ fused lambda GEMM) ----------
__global__ __launch_bounds__(256) void chunk_local(
    const ushort_t* __restrict__ rxh, const ushort_t* __restrict__ kxh,
    const float* __restrict__ vx, const ushort_t* __restrict__ t5d,
    const ushort_t* __restrict__ w2t, const float* __restrict__ tdec,
    const float* __restrict__ u, float* __restrict__ Mt,
    float* __restrict__ aLg, ushort_t* __restrict__ rAg,
    ushort_t* __restrict__ yo) {
  int c = blockIdx.x, bh = blockIdx.y;
  int b = bh >> 4, h = bh & 15;
  __shared__ ushort_t sRA[64 * 64], sKA[64 * 64], sKh[64 * 64], sKl[64 * 64],
                      sVh[64 * 64], sVl[64 * 64], sP[64 * 64];
  __shared__ float sLam[64 * 64];   // 16KB: lambda tile [t][i]
  __shared__ float qsum[4][64];
  __shared__ float ruk[64];
  const int tid = threadIdx.x;
  const int i = tid & 63;       // channel lane
  const int q = tid >> 6;       // t-quarter / wave
  size_t base = ((size_t)b * T_ + (size_t)c * CHL) * C_ + h * 64;
  size_t cb = ((size_t)c * 32 + bh);
  const int trow0 = b * T_ + c * CHL;

  const int lr0 = tid & 15, hi0 = (tid & 63) >> 4;

  // ---- phase 0: fused lambda GEMM: sLam[t][i] = exp(tdec + t5d@w2) --------
#pragma unroll
  for (int p = 0; p < 2; ++p) {
    int L = p * 256 + tid;
    int r = L >> 3, u8 = L & 7;
    int sc = (u8 ^ (r & 7)) * 8;
    gload16(t5d + (size_t)(trow0 + r) * 128 + sc, (char*)sRA + L * 16);
    gload16(w2t + (size_t)(h * 64 + r) * 64 + sc, (char*)sKA + L * 16);
  }
  asm volatile("s_waitcnt vmcnt(0)" ::: "memory");
  __syncthreads();
  {
    f32x4 accL[4] = {};
#pragma unroll
    for (int kk = 0; kk < 2; ++kk) {
      bf16x8 bw = ldb(sKA, q * 16 + lr0, kk * 64 + hi0 * 16);
#pragma unroll
      for (int mi = 0; mi < 4; ++mi) {
        bf16x8 at = ldb(sRA, mi * 16 + lr0, kk * 64 + hi0 * 16);
        accL[mi] = __builtin_amdgcn_mfma_f32_16x16x32_bf16(at, bw, accL[mi], 0, 0, 0);
      }
    }
    float tdv = tdec[h * 64 + q * 16 + lr0];
#pragma unroll
    for (int mi = 0; mi < 4; ++mi)
#pragma unroll
      for (int rr = 0; rr < 4; ++rr)
        sLam[(mi * 16 + hi0 * 4 + rr) * 64 + q * 16 + lr0] = __expf(tdv + accL[mi][rr]);
  }
  __syncthreads();

  // ---- phase A: lambda cumsum + tile builds ----
  float lam[16];
  float run = 0.f;
#pragma unroll
  for (int s = 0; s < 16; ++s) {
    lam[s] = sLam[(q * 16 + s) * 64 + i];
    run += lam[s];
  }
  qsum[q][i] = run;
  __syncthreads();
  float pre = 0.f, ct = 0.f;
#pragma unroll
  for (int qq = 0; qq < 4; ++qq) {
    float vq = qsum[qq][i];
    ct += vq;
    if (qq < q) pre += vq;
  }
  float uu = u[h * 64 + i];
  float ci = pre;
#pragma unroll
  for (int s = 0; s < 16; ++s) {
    int t = q * 16 + s;
    ci += lam[s];
    float cl = ci - lam[s];
    size_t o = base + (size_t)t * C_ + i;
    float rv = bf2f(rxh[o]), kv = bf2f(kxh[o]), vv = vx[o];
    ushort_t ra = f2bf(rv * __expf(-cl));
    stb(sRA, t, i, ra);
    rAg[cb * 4096 + t * 64 + i] = ra;
    stb(sKA, t, i, f2bf(kv * __expf(ci)));
    float kal = kv * __expf(ci - ct);
    ushort_t khv = f2bf(kal);
    stb(sKh, i, t, khv);
    stb(sKl, i, t, f2bf(kal - bf2f(khv)));
    ushort_t vhv = f2bf(vv);
    stb(sVh, i, t, vhv);
    stb(sVl, i, t, f2bf(vv - bf2f(vhv)));
    float rr = rv * uu * kv;
#pragma unroll
    for (int m = 32; m; m >>= 1) rr += __shfl_xor(rr, m);
    if (i == 0) ruk[t] = rr;
  }
  if (q == 0) aLg[cb * 64 + i] = __expf(-ct);
  __syncthreads();

  const int l = tid & 63, w = tid >> 6;
  const int wm = w >> 1, wn = w & 1;
  const int lr = l & 15, hi4 = l >> 4;

  // ---- phase B: P = rA @ kA^T, mask, store bf16 ----
  {
    f32x4 accP[2][2] = {};
#pragma unroll
    for (int kk = 0; kk < 2; ++kk) {
      bf16x8 af[2], bf_[2];
#pragma unroll
      for (int mi = 0; mi < 2; ++mi) af[mi] = ldb(sRA, wm * 32 + mi * 16 + lr, kk * 64 + hi4 * 16);
#pragma unroll
      for (int ni = 0; ni < 2; ++ni) bf_[ni] = ldb(sKA, wn * 32 + ni * 16 + lr, kk * 64 + hi4 * 16);
#pragma unroll
      for (int mi = 0; mi < 2; ++mi)
#pragma unroll
        for (int ni = 0; ni < 2; ++ni)
          accP[mi][ni] = __builtin_amdgcn_mfma_f32_16x16x32_bf16(af[mi], bf_[ni], accP[mi][ni], 0, 0, 0);
    }
#pragma unroll
    for (int mi = 0; mi < 2; ++mi)
#pragma unroll
      for (int ni = 0; ni < 2; ++ni)
#pragma unroll
        for (int r = 0; r < 4; ++r) {
          int tl = wm * 32 + mi * 16 + hi4 * 4 + r, sl = wn * 32 + ni * 16 + lr;
          float v = accP[mi][ni][r];
          v = sl < tl ? v : (sl == tl ? ruk[tl] : 0.f);
          stb(sP, tl, sl, f2bf(v));
        }
  }
  __syncthreads();

  // ---- phase C: y_intra = P@(Vh+Vl);  Mt = (Vh+Vl)^T @ (kh+kl) ----
  f32x4 accY[2][2] = {}, accM[2][2] = {};
#pragma unroll
  for (int kk = 0; kk < 2; ++kk) {
    bf16x8 pa[2], vhA[2], vlA[2], vhB[2], vlB[2], khB[2], klB[2];
#pragma unroll
    for (int mi = 0; mi < 2; ++mi) {
      int rw = wm * 32 + mi * 16 + lr;
      pa[mi] = ldb(sP, rw, kk * 64 + hi4 * 16);
      vhA[mi] = ldb(sVh, rw, kk * 64 + hi4 * 16);
      vlA[mi] = ldb(sVl, rw, kk * 64 + hi4 * 16);
    }
#pragma unroll
    for (int ni = 0; ni < 2; ++ni) {
      int rw = wn * 32 + ni * 16 + lr;
      vhB[ni] = ldb(sVh, rw, kk * 64 + hi4 * 16);
      vlB[ni] = ldb(sVl, rw, kk * 64 + hi4 * 16);
      khB[ni] = ldb(sKh, rw, kk * 64 + hi4 * 16);
      klB[ni] = ldb(sKl, rw, kk * 64 + hi4 * 16);
    }
#pragma unroll
    for (int mi = 0; mi < 2; ++mi)
#pragma unroll
      for (int ni = 0; ni < 2; ++ni) {
        accY[mi][ni] = __builtin_amdgcn_mfma_f32_16x16x32_bf16(pa[mi], vhB[ni], accY[mi][ni], 0, 0, 0);
        accY[mi][ni] = __builtin_amdgcn_mfma_f32_16x16x32_bf16(pa[mi], vlB[ni], accY[mi][ni], 0, 0, 0);
        accM[mi][ni] = __builtin_amdgcn_mfma_f32_16x16x32_bf16(vhA[mi], khB[ni], accM[mi][ni], 0, 0, 0);
        accM[mi][ni] = __builtin_amdgcn_mfma_f32_16x16x32_bf16(vhA[mi], klB[ni], accM[mi][ni], 0, 0, 0);
        accM[mi][ni] = __builtin_amdgcn_mfma_f32_16x16x32_bf16(vlA[mi], khB[ni], accM[mi][ni], 0, 0, 0);
      }
  }
#pragma unroll
  for (int mi = 0; mi < 2; ++mi)
#pragma unroll
    for (int ni = 0; ni < 2; ++ni)
#pragma unroll
      for (int r = 0; r < 4; ++r) {
        int rw = wm * 32 + mi * 16 + hi4 * 4 + r;
        int cw = wn * 32 + ni * 16 + lr;
        yo[base + (size_t)rw * C_ + cw] = f2bf(accY[mi][ni][r]);  // y_intra bf16
        Mt[cb * 4096 + rw * 64 + cw] = accM[mi][ni][r];           // Mt[j][i]
      }
}

// ---------------- K2: sequential chunk combine (prefetched, vec4) ----------
__global__ __launch_bounds__(128) void combine2(
    const float* __restrict__ Mt, const float* __restrict__ aLg,
    ushort_t* __restrict__ S0h, ushort_t* __restrict__ S0l) {
  int bh = blockIdx.x >> 3;
  int ij = ((blockIdx.x & 7) * 128 + threadIdx.x) * 4;   // [j][i] linear, 4-wide
  int i = ij & 63;
  const float* Mp = Mt + (size_t)bh * 4096 + ij;
  const float* Pp = aLg + (size_t)bh * 64 + i;
  ushort_t* Hp = S0h + (size_t)bh * 4096 + ij;
  ushort_t* Lp = S0l + (size_t)bh * 4096 + ij;
  float4 s = {0.f, 0.f, 0.f, 0.f};
  float4 m = *(const float4*)Mp;
  float4 p = *(const float4*)Pp;
  for (int c = 0; c < NCH; ++c) {
    float4 mn, pn;
    if (c < NCH - 1) {
      mn = *(const float4*)(Mp + (size_t)(c + 1) * (32 * 4096));
      pn = *(const float4*)(Pp + (size_t)(c + 1) * (32 * 64));
    }
    size_t o = (size_t)c * (32 * 4096);
    ushort4 hi, lo;
    hi.x = f2bf(s.x); lo.x = f2bf(s.x - bf2f(hi.x));
    hi.y = f2bf(s.y); lo.y = f2bf(s.y - bf2f(hi.y));
    hi.z = f2bf(s.z); lo.z = f2bf(s.z - bf2f(hi.z));
    hi.w = f2bf(s.w); lo.w = f2bf(s.w - bf2f(hi.w));
    *(ushort4*)(Hp + o) = hi;
    *(ushort4*)(Lp + o) = lo;
    s.x = p.x * s.x + m.x; s.y = p.y * s.y + m.y;
    s.z = p.z * s.z + m.z; s.w = p.w * s.w + m.w;
    m = mn; p = pn;
  }
}

// ---------------- K3: y = y_intra + rA@S0, GroupNorm, *g -> bf16 Z ---------
__global__ __launch_bounds__(256) void inter_gn(
    const ushort_t* __restrict__ rAg, const ushort_t* __restrict__ S0h,
    const ushort_t* __restrict__ S0l, const ushort_t* __restrict__ yin,
    const ushort_t* __restrict__ gx, const float* __restrict__ lnw,
    const float* __restrict__ lnb, ushort_t* __restrict__ Z) {
  int c = blockIdx.x, bh = blockIdx.y;
  int b = bh >> 4, h = bh & 15;
  __shared__ ushort_t sRA[64 * 64], sSh[64 * 64], sSl[64 * 64];
  __shared__ float st[64][2][2];
  const int tid = threadIdx.x;
  size_t cb = ((size_t)c * 32 + bh) * 4096;
#pragma unroll
  for (int it = 0; it < 2; ++it) {
    int lb = tid * 32 + it * 16;
    int row = lb >> 7, wi = lb & 127;
    int so = row * 128 + (wi ^ ((row & 7) << 4));
    *(uint4*)((char*)sRA + so) = *(const uint4*)((const char*)(rAg + cb) + lb);
    *(uint4*)((char*)sSh + so) = *(const uint4*)((const char*)(S0h + cb) + lb);
    *(uint4*)((char*)sSl + so) = *(const uint4*)((const char*)(S0l + cb) + lb);
  }
  const int l = tid & 63, w = tid >> 6;
  const int wm = w >> 1, wn = w & 1;
  const int lr = l & 15, hi4 = l >> 4;
  size_t base = ((size_t)b * T_ + (size_t)c * CHL) * C_ + h * 64;

  f32x4 acc[2][2];
#pragma unroll
  for (int mi = 0; mi < 2; ++mi)
#pragma unroll
    for (int ni = 0; ni < 2; ++ni)
#pragma unroll
      for (int r = 0; r < 4; ++r)
        acc[mi][ni][r] = bf2f(yin[base + (size_t)(wm * 32 + mi * 16 + hi4 * 4 + r) * C_ +
                                  wn * 32 + ni * 16 + lr]);
  __syncthreads();
#pragma unroll
  for (int kk = 0; kk < 2; ++kk) {
    bf16x8 af[2], bh_[2], bl_[2];
#pragma unroll
    for (int mi = 0; mi < 2; ++mi) af[mi] = ldb(sRA, wm * 32 + mi * 16 + lr, kk * 64 + hi4 * 16);
#pragma unroll
    for (int ni = 0; ni < 2; ++ni) {
      bh_[ni] = ldb(sSh, wn * 32 + ni * 16 + lr, kk * 64 + hi4 * 16);
      bl_[ni] = ldb(sSl, wn * 32 + ni * 16 + lr, kk * 64 + hi4 * 16);
    }
#pragma unroll
    for (int mi = 0; mi < 2; ++mi)
#pragma unroll
      for (int ni = 0; ni < 2; ++ni) {
        acc[mi][ni] = __builtin_amdgcn_mfma_f32_16x16x32_bf16(af[mi], bh_[ni], acc[mi][ni], 0, 0, 0);
        acc[mi][ni] = __builtin_amdgcn_mfma_f32_16x16x32_bf16(af[mi], bl_[ni], acc[mi][ni], 0, 0, 0);
      }
  }
#pragma unroll
  for (int mi = 0; mi < 2; ++mi)
#pragma unroll
    for (int r = 0; r < 4; ++r) {
      int row = wm * 32 + mi * 16 + hi4 * 4 + r;
      float s1 = acc[mi][0][r] + acc[mi][1][r];
      float s2 = acc[mi][0][r] * acc[mi][0][r] + acc[mi][1][r] * acc[mi][1][r];
#pragma unroll
      for (int m = 1; m < 16; m <<= 1) { s1 += __shfl_xor(s1, m); s2 += __shfl_xor(s2, m); }
      if (lr == 0) { st[row][wn][0] = s1; st[row][wn][1] = s2; }
    }
  __syncthreads();
#pragma unroll
  for (int mi = 0; mi < 2; ++mi)
#pragma unroll
    for (int ni = 0; ni < 2; ++ni)
#pragma unroll
      for (int r = 0; r < 4; ++r) {
        int row = wm * 32 + mi * 16 + hi4 * 4 + r;
        int jl = wn * 32 + ni * 16 + lr;
        float S1 = st[row][0][0] + st[row][1][0];
        float S2 = st[row][0][1] + st[row][1][1];
        float mu = S1 * (1.f / 64.f);
        float var = S2 * (1.f / 64.f) - mu * mu;
        float rs = rsqrtf(var + 6.4e-4f);          // EPS = 1e-5 * 64
        int col = h * 64 + jl;
        size_t o = base + (size_t)row * C_ + jl;
        float yn = (acc[mi][ni][r] - mu) * rs * lnw[col] + lnb[col];
        Z[o] = f2bf(yn * bf2f(gx[o]));
      }
}

// ===========================================================================
extern "C" void kernel_launch(void* const* d_in, const int* in_sizes, int n_in,
                              void* d_out, int out_size, void* d_ws, size_t ws_size,
                              hipStream_t stream) {
  const float* x    = (const float*)d_in[0];
  const float* tmx  = (const float*)d_in[1];
  const float* tmw  = (const float*)d_in[2];
  const float* tmk  = (const float*)d_in[3];
  const float* tmv  = (const float*)d_in[4];
  const float* tmr  = (const float*)d_in[5];
  const float* tmg  = (const float*)d_in[6];
  const float* maaw1 = (const float*)d_in[7];
  const float* maaw2 = (const float*)d_in[8];
  const float* tdec = (const float*)d_in[9];
  const float* tdw1 = (const float*)d_in[10];
  const float* tdw2 = (const float*)d_in[11];
  const float* u    = (const float*)d_in[12];
  const float* Wr   = (const float*)d_in[13];
  const float* Wk   = (const float*)d_in[14];
  const float* Wv   = (const float*)d_in[15];
  const float* Wg   = (const float*)d_in[16];
  const float* Wo   = (const float*)d_in[17];
  const float* lnw  = (const float*)d_in[18];
  const float* lnb  = (const float*)d_in[19];

  char* ws = (char*)d_ws;
  const size_t MB = 1ull << 20;
  ushort_t* xh     = (ushort_t*)(ws + 0);         // 8MB  (later: yb)
  ushort_t* xxh    = (ushort_t*)(ws + 8 * MB);    // 8MB
  ushort_t* xxx    = (ushort_t*)(ws + 16 * MB);   // 8MB  (later: Zb)
  ushort_t* WrT    = (ushort_t*)(ws + 24 * MB);
  ushort_t* WkT    = (ushort_t*)(ws + 26 * MB);
  ushort_t* WvT    = (ushort_t*)(ws + 28 * MB);
  ushort_t* WgT    = (ushort_t*)(ws + 30 * MB);
  ushort_t* WoT    = (ushort_t*)(ws + 32 * MB);
  ushort_t* maaW1T = (ushort_t*)(ws + 34 * MB);              // 256x1024
  ushort_t* tdW1T  = (ushort_t*)(ws + 35 * MB);              // 128x1024
  ushort_t* tdW2T  = (ushort_t*)(ws + 35 * MB + 256 * 1024); // 1024x64
  ushort_t* maaW2T = (ushort_t*)(ws + 35 * MB + 512 * 1024); // 1024x160
  ushort_t* t5     = (ushort_t*)(ws + 36 * MB);   // 4096x256 bf16
  ushort_t* t5d    = (ushort_t*)(ws + 38 * MB);   // 4096x128 bf16
  ushort_t* Xm[5];
  for (int f = 0; f < 5; ++f) Xm[f] = (ushort_t*)(ws + 40 * MB + (size_t)f * 8 * MB);
  float*    Mtb = (float*)(ws + 40 * MB);          // 16MB  (over Xm[0..1], dead)
  ushort_t* S0h = (ushort_t*)(ws + 56 * MB);       // 8MB   (over Xm[2])
  ushort_t* S0l = (ushort_t*)(ws + 64 * MB);       // 8MB   (over Xm[3])
  ushort_t* rAg = (ushort_t*)(ws + 72 * MB);       // 8MB   (over Xm[4])
  ushort_t* rbh = (ushort_t*)(ws + 80 * MB);       // 8MB bf16 r
  ushort_t* kbh = (ushort_t*)(ws + 96 * MB);       // 8MB bf16 k
  float* vb   = (float*)(ws + 112 * MB);
  ushort_t* gbh = (ushort_t*)(ws + 128 * MB);      // 8MB bf16 gate
  float* aLg  = (float*)(ws + 144 * MB);           // 256KB
  ushort_t* yb = (ushort_t*)(ws + 0);              // bf16, alias xh (dead by then)
  ushort_t* Zb = (ushort_t*)(ws + 16 * MB);        // alias xxx (dead by then)

  // 1) weight transposes/converts + token-shift prep in ONE launch
  TArgs ta;
  ta.d[0] = TDesc{Wr,    WrT,    1024, 1024, 1024};
  ta.d[1] = TDesc{Wk,    WkT,    1024, 1024, 1024};
  ta.d[2] = TDesc{Wv,    WvT,    1024, 1024, 1024};
  ta.d[3] = TDesc{Wg,    WgT,    1024, 1024, 1024};
  ta.d[4] = TDesc{Wo,    WoT,    1024, 1024, 1024};
  ta.d[5] = TDesc{maaw1, maaW1T, 1024, 160,  256};
  ta.d[6] = TDesc{tdw1,  tdW1T,  1024, 64,   128};
  ta.d[7] = TDesc{tdw2,  tdW2T,  64,   1024, 1024};
  ta.d[8] = TDesc{maaw2, maaW2T, 160,  1024, 1024};
  init_kernel<<<dim3(32, 32, 10), 256, 0, stream>>>(ta, x, tmx, xh, xxh, xxx);

  // 2) t5 = tanh(xxx @ maa_w1)  (32-row tiles: 256 blocks, full CU coverage)
  gemm_bt32<<<dim3(128, 2), 256, 0, stream>>>(xxx, C_, maaW1T, C_, t5, 256, C_);

  // 3) fused per-f mix (bf16 staging)
  MixArgs ma;
  ma.tm[0] = tmw; ma.tm[1] = tmk; ma.tm[2] = tmv; ma.tm[3] = tmr; ma.tm[4] = tmg;
  for (int f = 0; f < 5; ++f) ma.dst[f] = Xm[f];
  fused_mix<<<dim3(64, 8), 256, 0, stream>>>(xh, xxh, t5, maaW2T, ma);

  // 4) projections r,k,v,g — 256² 8-phase (r,k -> bf16, g -> silu bf16)
  PArgs pa;
  pa.d[0] = PDesc{Xm[3], WrT, rbh, 3};
  pa.d[1] = PDesc{Xm[1], WkT, kbh, 3};
  pa.d[2] = PDesc{Xm[2], WvT, vb, 0};
  pa.d[3] = PDesc{Xm[4], WgT, gbh, 2};
  gemm_proj256<<<dim3(16, 4, 4), 512, 0, stream>>>(pa);

  // 5) decay part 1 only: t5d = tanh(xw @ td_w1); lambda fused into scan
  gemm_bt32<<<dim3(128, 1), 256, 0, stream>>>(Xm[0], C_, tdW1T, C_, t5d, 128, C_);

  // 6) MFMA chunked scan (fused lambda GEMM; y_intra in bf16)
  chunk_local<<<dim3(NCH, B_ * H_), 256, 0, stream>>>(rbh, kbh, vb, t5d, tdW2T, tdec,
                                                      u, Mtb, aLg, rAg, yb);
  combine2<<<256, 128, 0, stream>>>(Mtb, aLg, S0h, S0l);
  inter_gn<<<dim3(NCH, B_ * H_), 256, 0, stream>>>(rAg, S0h, S0l, yb, gbh, lnw, lnb, Zb);

  // 7) out = Z @ Wo — 128² tile, 256 blocks (full CU coverage)
  gemm_bt<<<dim3(32, 8), 256, 0, stream>>>(Zb, C_, WoT, C_, (float*)d_out, C_, C_);
}